// Round 8
// baseline (476.070 us; speedup 1.0000x reference)
//
#include <hip/hip_runtime.h>
#include <hip/hip_bf16.h>

#define NN 100000
#define EE 1600000
#define RR 8
#define DD 64
#define MM (NN * RR)                 // 800000 (dst,rel) segments
#define BN_EPS 1e-5f
#define KTOT 576                     // 512 (rel) + 64 (root)
#define APITCH 584                   // LDS A row pitch in shorts (292 words % 32 = 4)

// bucket sort params: 256 dsts per bucket -> 2048 (dst,rel) keys per bucket
#define NB 391                       // ceil(100000/256)
#define EPB 8192                     // edges per block in binning kernels
#define NBIN ((EE + EPB - 1) / EPB)  // 196

typedef __bf16 bf16x8 __attribute__((ext_vector_type(8)));
typedef float  f32x4  __attribute__((ext_vector_type(4)));

static __device__ __forceinline__ unsigned short f32_to_bf16(float f) {
    unsigned int u = __float_as_uint(f);
    unsigned int r = u + 0x7FFFu + ((u >> 16) & 1u);   // RNE
    return (unsigned short)(r >> 16);
}
static __device__ __forceinline__ float bflo(unsigned int u) {
    return __uint_as_float(u << 16);
}
static __device__ __forceinline__ float bfhi(unsigned int u) {
    return __uint_as_float(u & 0xFFFF0000u);
}

// ---------------- bucketed CSR build ----------------

__global__ void k_bcount(const int* __restrict__ dst, int* __restrict__ btot) {
    __shared__ int cnt[NB];
    int t = threadIdx.x;
    for (int i = t; i < NB; i += 256) cnt[i] = 0;
    __syncthreads();
    int base = blockIdx.x * EPB;
#pragma unroll
    for (int i = 0; i < EPB / 256; ++i) {
        int e = base + i * 256 + t;
        if (e < EE) atomicAdd(&cnt[dst[e] >> 8], 1);
    }
    __syncthreads();
    for (int i = t; i < NB; i += 256)
        if (cnt[i]) atomicAdd(&btot[i], cnt[i]);
}

__global__ void k_bscan(const int* __restrict__ btot, int* __restrict__ bbase,
                        int* __restrict__ gcur, int* __restrict__ rowptr) {
    __shared__ int sd[512];
    int t = threadIdx.x;
    int v = (t < NB) ? btot[t] : 0;
    sd[t] = v;
    __syncthreads();
    for (int off = 1; off < 512; off <<= 1) {
        int x = (t >= off) ? sd[t - off] : 0;
        __syncthreads();
        sd[t] += x;
        __syncthreads();
    }
    if (t < NB) { bbase[t] = sd[t] - v; gcur[t] = sd[t] - v; }
    if (t == NB - 1) { bbase[NB] = sd[t]; rowptr[MM] = sd[t]; }
}

// bin edges into bucket-contiguous ebuf, packed: src | (localkey << 17)
__global__ void k_bin(const int* __restrict__ src, const int* __restrict__ dst,
                      const int* __restrict__ et, int* __restrict__ gcur,
                      unsigned int* __restrict__ ebuf) {
    __shared__ int cnt[NB];
    __shared__ int bas[NB];
    __shared__ int off[NB];
    int t = threadIdx.x;
    for (int i = t; i < NB; i += 256) { cnt[i] = 0; off[i] = 0; }
    __syncthreads();
    int base = blockIdx.x * EPB;
#pragma unroll
    for (int i = 0; i < EPB / 256; ++i) {
        int e = base + i * 256 + t;
        if (e < EE) atomicAdd(&cnt[dst[e] >> 8], 1);
    }
    __syncthreads();
    for (int i = t; i < NB; i += 256) {
        int c = cnt[i];
        bas[i] = c ? atomicAdd(&gcur[i], c) : 0;
    }
    __syncthreads();
#pragma unroll
    for (int i = 0; i < EPB / 256; ++i) {
        int e = base + i * 256 + t;
        if (e < EE) {
            int d = dst[e];
            int b = d >> 8;
            int lk = ((d & 255) << 3) | et[e];
            unsigned int rec0 = (unsigned int)src[e] | ((unsigned int)lk << 17);
            int p = bas[b] + atomicAdd(&off[b], 1);
            ebuf[p] = rec0;
        }
    }
}

// per-bucket: LDS histogram + scan -> rowptr; LDS cursors -> sorted rec
__global__ __launch_bounds__(256) void k_bcsr(const int* __restrict__ bbase,
                                              const unsigned int* __restrict__ ebuf,
                                              int* __restrict__ rowptr,
                                              int* __restrict__ rec) {
    __shared__ int deg[2048];
    __shared__ int part[256];
    int b = blockIdx.x, t = threadIdx.x;
    int e0 = bbase[b], e1 = bbase[b + 1];
    for (int i = t; i < 2048; i += 256) deg[i] = 0;
    __syncthreads();
    for (int e = e0 + t; e < e1; e += 256) atomicAdd(&deg[ebuf[e] >> 17], 1);
    __syncthreads();
    int loc[8];
    int s = 0;
#pragma unroll
    for (int j = 0; j < 8; ++j) { loc[j] = deg[t * 8 + j]; s += loc[j]; }
    part[t] = s;
    __syncthreads();
    for (int off = 1; off < 256; off <<= 1) {
        int x = (t >= off) ? part[t - off] : 0;
        __syncthreads();
        part[t] += x;
        __syncthreads();
    }
    int run = part[t] - s;
    int keyBase = b * 2048;
#pragma unroll
    for (int j = 0; j < 8; ++j) {
        int g = keyBase + t * 8 + j;
        if (g < MM) rowptr[g] = e0 + run;
        deg[t * 8 + j] = run;
        run += loc[j];
    }
    __syncthreads();
    for (int e = e0 + t; e < e1; e += 256) {
        unsigned int v = ebuf[e];
        int lk = v >> 17;
        int pos = e0 + atomicAdd(&deg[lk], 1);
        rec[pos] = (int)(v & 0x1FFFFu);
    }
}

// ---------------- fp32 -> bf16 row conversion ----------------

__global__ void k_tobf16(const float* __restrict__ X, unsigned short* __restrict__ Xb) {
    int i = blockIdx.x * 256 + threadIdx.x;
    if (i >= NN * DD / 4) return;
    float4 v = ((const float4*)X)[i];
    ushort4 o;
    o.x = f32_to_bf16(v.x); o.y = f32_to_bf16(v.y);
    o.z = f32_to_bf16(v.z); o.w = f32_to_bf16(v.w);
    ((ushort4*)Xb)[i] = o;
}

// ---------------- weight prep: WcT[64][576] bf16, k = r*64+d (+root tail) ----------------

__global__ void k_prepw(const float* __restrict__ W, const float* __restrict__ Root,
                        unsigned short* __restrict__ WcT) {
    int i = blockIdx.x * 256 + threadIdx.x;
    if (i >= 64 * KTOT) return;
    int o = i / KTOT;
    int k = i - o * KTOT;
    float v;
    if (k < 512) v = W[(size_t)(k >> 6) * 4096 + (k & 63) * 64 + o];
    else         v = Root[(k - 512) * 64 + o];
    WcT[(size_t)o * KTOT + k] = f32_to_bf16(v);
}

// ---------------- fused aggregation + MFMA GEMM ----------------
// Block = 16 nodes. Phase 1: wave wv aggregates nodes n0+wv*4 .. +3 (8 lanes
// per (dst,rel) segment), stores bf16 mean rows + own-Xb tail into LDS
// As[16][584] (K = 576 per row). Phase 2: wave wv computes the 16x16 output
// col-tile nt=wv over K=576: A from LDS, B (WcT) from global (L2-hot).
// Optional fused BN column stats.

__global__ __launch_bounds__(256) void k_aggemm(const unsigned short* __restrict__ Xb,
                                                const int* __restrict__ rowptr,
                                                const int* __restrict__ rec,
                                                const unsigned short* __restrict__ WcT,
                                                const float* __restrict__ bias,
                                                float* __restrict__ Out,
                                                float* __restrict__ stats,
                                                int dostats) {
    __shared__ unsigned short As[16 * APITCH];   // 18.25 KB
    int t = threadIdx.x;
    int wv = t >> 6, lane = t & 63;
    int n0 = blockIdx.x * 16;
    int r = lane >> 3;       // segment 0..7
    int q = lane & 7;        // dim-octet 0..7

#pragma unroll 1
    for (int j = 0; j < 4; ++j) {
        int row = wv * 4 + j;
        int n = n0 + row;
        int e0 = rowptr[n * RR + r];
        int e1 = rowptr[n * RR + r + 1];
        float a0[8] = {0,0,0,0,0,0,0,0};
        float a1[8] = {0,0,0,0,0,0,0,0};
        float a2[8] = {0,0,0,0,0,0,0,0};
        float a3[8] = {0,0,0,0,0,0,0,0};
        int e = e0;
        for (; e + 3 < e1; e += 4) {
            int s0 = rec[e], s1 = rec[e + 1], s2 = rec[e + 2], s3 = rec[e + 3];
            uint4 u0 = *(const uint4*)(Xb + (size_t)s0 * DD + q * 8);
            uint4 u1 = *(const uint4*)(Xb + (size_t)s1 * DD + q * 8);
            uint4 u2 = *(const uint4*)(Xb + (size_t)s2 * DD + q * 8);
            uint4 u3 = *(const uint4*)(Xb + (size_t)s3 * DD + q * 8);
            a0[0] += bflo(u0.x); a0[1] += bfhi(u0.x); a0[2] += bflo(u0.y); a0[3] += bfhi(u0.y);
            a0[4] += bflo(u0.z); a0[5] += bfhi(u0.z); a0[6] += bflo(u0.w); a0[7] += bfhi(u0.w);
            a1[0] += bflo(u1.x); a1[1] += bfhi(u1.x); a1[2] += bflo(u1.y); a1[3] += bfhi(u1.y);
            a1[4] += bflo(u1.z); a1[5] += bfhi(u1.z); a1[6] += bflo(u1.w); a1[7] += bfhi(u1.w);
            a2[0] += bflo(u2.x); a2[1] += bfhi(u2.x); a2[2] += bflo(u2.y); a2[3] += bfhi(u2.y);
            a2[4] += bflo(u2.z); a2[5] += bfhi(u2.z); a2[6] += bflo(u2.w); a2[7] += bfhi(u2.w);
            a3[0] += bflo(u3.x); a3[1] += bfhi(u3.x); a3[2] += bflo(u3.y); a3[3] += bfhi(u3.y);
            a3[4] += bflo(u3.z); a3[5] += bfhi(u3.z); a3[6] += bflo(u3.w); a3[7] += bfhi(u3.w);
        }
        if (e + 1 < e1) {
            int s0 = rec[e], s1 = rec[e + 1];
            uint4 u0 = *(const uint4*)(Xb + (size_t)s0 * DD + q * 8);
            uint4 u1 = *(const uint4*)(Xb + (size_t)s1 * DD + q * 8);
            a0[0] += bflo(u0.x); a0[1] += bfhi(u0.x); a0[2] += bflo(u0.y); a0[3] += bfhi(u0.y);
            a0[4] += bflo(u0.z); a0[5] += bfhi(u0.z); a0[6] += bflo(u0.w); a0[7] += bfhi(u0.w);
            a1[0] += bflo(u1.x); a1[1] += bfhi(u1.x); a1[2] += bflo(u1.y); a1[3] += bfhi(u1.y);
            a1[4] += bflo(u1.z); a1[5] += bfhi(u1.z); a1[6] += bflo(u1.w); a1[7] += bfhi(u1.w);
            e += 2;
        }
        if (e < e1) {
            int s0 = rec[e];
            uint4 u0 = *(const uint4*)(Xb + (size_t)s0 * DD + q * 8);
            a0[0] += bflo(u0.x); a0[1] += bfhi(u0.x); a0[2] += bflo(u0.y); a0[3] += bfhi(u0.y);
            a0[4] += bflo(u0.z); a0[5] += bfhi(u0.z); a0[6] += bflo(u0.w); a0[7] += bfhi(u0.w);
        }
        int cnt = e1 - e0;
        float inv = 1.0f / (float)(cnt > 1 ? cnt : 1);
        uint4 o;
        o.x = (unsigned)f32_to_bf16((a0[0]+a1[0]+a2[0]+a3[0]) * inv) | ((unsigned)f32_to_bf16((a0[1]+a1[1]+a2[1]+a3[1]) * inv) << 16);
        o.y = (unsigned)f32_to_bf16((a0[2]+a1[2]+a2[2]+a3[2]) * inv) | ((unsigned)f32_to_bf16((a0[3]+a1[3]+a2[3]+a3[3]) * inv) << 16);
        o.z = (unsigned)f32_to_bf16((a0[4]+a1[4]+a2[4]+a3[4]) * inv) | ((unsigned)f32_to_bf16((a0[5]+a1[5]+a2[5]+a3[5]) * inv) << 16);
        o.w = (unsigned)f32_to_bf16((a0[6]+a1[6]+a2[6]+a3[6]) * inv) | ((unsigned)f32_to_bf16((a0[7]+a1[7]+a2[7]+a3[7]) * inv) << 16);
        *(uint4*)(As + row * APITCH + r * 64 + q * 8) = o;
        if (r == 0) {   // K-tail: node's own Xb row (root term)
            uint4 xo = *(const uint4*)(Xb + (size_t)n * DD + q * 8);
            *(uint4*)(As + row * APITCH + 512 + q * 8) = xo;
        }
    }
    __syncthreads();

    // GEMM phase: wave wv -> output cols wv*16..+15, rows 0..15 (block nodes)
    int quad = lane >> 4, m16 = lane & 15;
    union AU { uint4 u; bf16x8 f; };
    f32x4 acc = {0.f, 0.f, 0.f, 0.f};
    const unsigned short* ap = As + m16 * APITCH + quad * 8;
    const unsigned short* wp = WcT + (size_t)(wv * 16 + m16) * KTOT + quad * 8;
#pragma unroll
    for (int kb = 0; kb < 18; ++kb) {
        AU a, b;
        a.u = *(const uint4*)(ap + kb * 32);
        b.u = *(const uint4*)(wp + kb * 32);
        acc = __builtin_amdgcn_mfma_f32_16x16x32_bf16(a.f, b.f, acc, 0, 0, 0);
    }

    int col = wv * 16 + m16;
    float bb = bias[col];
    float s = 0.f, sq = 0.f;
#pragma unroll
    for (int i = 0; i < 4; ++i) {
        int row = quad * 4 + i;
        float v = acc[i] + bb;
        Out[(size_t)(n0 + row) * 64 + col] = v;
        s += v; sq += v * v;
    }
    if (dostats) {
        s += __shfl_xor(s, 16); s += __shfl_xor(s, 32);
        sq += __shfl_xor(sq, 16); sq += __shfl_xor(sq, 32);
        if (quad == 0) {
            atomicAdd(&stats[col], s);
            atomicAdd(&stats[64 + col], sq);
        }
    }
}

// ---------------- BN+ReLU (in-place, + bf16 copy) ----------------

__global__ void k_bnrelu(float* __restrict__ H, unsigned short* __restrict__ Hb,
                         const float* __restrict__ stats,
                         const float* __restrict__ gamma, const float* __restrict__ beta) {
    int idx = blockIdx.x * 256 + threadIdx.x;
    const int total = NN * DD / 4;
    if (idx >= total) return;
    int c0 = (idx & 15) * 4;
    float4 v = ((const float4*)H)[idx];
    float inv = 1.0f / (float)NN;
    float4 o;
    {
        float mu = stats[c0 + 0] * inv;
        float var = stats[64 + c0 + 0] * inv - mu * mu;
        float sc = gamma[c0 + 0] * rsqrtf(var + BN_EPS);
        float r = sc * (v.x - mu) + beta[c0 + 0];
        o.x = r > 0.f ? r : 0.f;
    }
    {
        float mu = stats[c0 + 1] * inv;
        float var = stats[64 + c0 + 1] * inv - mu * mu;
        float sc = gamma[c0 + 1] * rsqrtf(var + BN_EPS);
        float r = sc * (v.y - mu) + beta[c0 + 1];
        o.y = r > 0.f ? r : 0.f;
    }
    {
        float mu = stats[c0 + 2] * inv;
        float var = stats[64 + c0 + 2] * inv - mu * mu;
        float sc = gamma[c0 + 2] * rsqrtf(var + BN_EPS);
        float r = sc * (v.z - mu) + beta[c0 + 2];
        o.z = r > 0.f ? r : 0.f;
    }
    {
        float mu = stats[c0 + 3] * inv;
        float var = stats[64 + c0 + 3] * inv - mu * mu;
        float sc = gamma[c0 + 3] * rsqrtf(var + BN_EPS);
        float r = sc * (v.w - mu) + beta[c0 + 3];
        o.w = r > 0.f ? r : 0.f;
    }
    ((float4*)H)[idx] = o;
    ushort4 ob;
    ob.x = f32_to_bf16(o.x); ob.y = f32_to_bf16(o.y);
    ob.z = f32_to_bf16(o.z); ob.w = f32_to_bf16(o.w);
    ((ushort4*)Hb)[idx] = ob;
}

// ---------------- launch ----------------

static inline size_t alignup(size_t x) { return (x + 255) & ~(size_t)255; }

extern "C" void kernel_launch(void* const* d_in, const int* in_sizes, int n_in,
                              void* d_out, int out_size, void* d_ws, size_t ws_size,
                              hipStream_t stream) {
    const float* x      = (const float*)d_in[0];
    const int*   eidx   = (const int*)d_in[1];
    const int*   etype  = (const int*)d_in[2];
    const float* w1     = (const float*)d_in[3];
    const float* root1  = (const float*)d_in[4];
    const float* b1     = (const float*)d_in[5];
    const float* gamma1 = (const float*)d_in[6];
    const float* beta1  = (const float*)d_in[7];
    const float* w2     = (const float*)d_in[8];
    const float* root2  = (const float*)d_in[9];
    const float* b2     = (const float*)d_in[10];
    float* out = (float*)d_out;

    const int* src = eidx;
    const int* dst = eidx + EE;

    char* w = (char*)d_ws;
    int* rowptr = (int*)w;            w += alignup((size_t)(MM + 1) * 4);
    int* btot   = (int*)w;            w += alignup(512 * 4);
    int* bbase  = (int*)w;            w += alignup(512 * 4);
    int* gcur   = (int*)w;            w += alignup(512 * 4);
    int* rec    = (int*)w;            w += alignup((size_t)EE * 4);
    unsigned int* ebuf = (unsigned int*)w; w += alignup((size_t)EE * 4);
    float* h    = (float*)w;          w += alignup((size_t)NN * DD * 4);
    unsigned short* xhb = (unsigned short*)w; w += alignup((size_t)NN * DD * 2);
    unsigned short* wct1 = (unsigned short*)w; w += alignup((size_t)64 * KTOT * 2);
    unsigned short* wct2 = (unsigned short*)w; w += alignup((size_t)64 * KTOT * 2);
    float* stats = (float*)w;         w += alignup(128 * 4);

    hipMemsetAsync(btot, 0, 512 * 4, stream);
    hipMemsetAsync(stats, 0, 128 * 4, stream);

    k_prepw<<<dim3(144), dim3(256), 0, stream>>>(w1, root1, wct1);
    k_prepw<<<dim3(144), dim3(256), 0, stream>>>(w2, root2, wct2);
    k_tobf16<<<dim3(NN * DD / 4 / 256 + 1), dim3(256), 0, stream>>>(x, xhb);

    // bucketed CSR build
    k_bcount<<<dim3(NBIN), dim3(256), 0, stream>>>(dst, btot);
    k_bscan<<<dim3(1), dim3(512), 0, stream>>>(btot, bbase, gcur, rowptr);
    k_bin<<<dim3(NBIN), dim3(256), 0, stream>>>(src, dst, etype, gcur, ebuf);
    k_bcsr<<<dim3(NB), dim3(256), 0, stream>>>(bbase, ebuf, rowptr, rec);

    // layer 1 (fused agg + gemm + BN column stats)
    k_aggemm<<<dim3(NN / 16), dim3(256), 0, stream>>>(xhb, rowptr, rec, wct1, b1, h, stats, 1);
    k_bnrelu<<<dim3(NN * DD / 4 / 256), dim3(256), 0, stream>>>(h, xhb, stats, gamma1, beta1);

    // layer 2 (xhb now holds bf16 of post-BN/ReLU h)
    k_aggemm<<<dim3(NN / 16), dim3(256), 0, stream>>>(xhb, rowptr, rec, wct2, b2, out, stats, 0);
}

// Round 9
// 450.271 us; speedup vs baseline: 1.0573x; 1.0573x over previous
//
#include <hip/hip_runtime.h>
#include <hip/hip_bf16.h>

#define NN 100000
#define EE 1600000
#define RR 8
#define DD 64
#define MM (NN * RR)                 // 800000 (dst,rel) segments
#define BN_EPS 1e-5f
#define KTOT 576                     // 512 (rel) + 64 (root)
#define APITCH 584                   // LDS A row pitch in shorts (292 words % 32 = 4)

// bucket sort params: 256 dsts per bucket -> 2048 (dst,rel) keys per bucket
#define NB 391                       // ceil(100000/256)
#define EPB 8192                     // edges per block in binning kernels
#define NBIN ((EE + EPB - 1) / EPB)  // 196

// merged prep kernel grid sections
#define PREPW_BLKS 144               // ceil(64*576/256)
#define TOBF_BLKS (NN * DD / 4 / 256)  // 6250

typedef __bf16 bf16x8 __attribute__((ext_vector_type(8)));
typedef float  f32x4  __attribute__((ext_vector_type(4)));

static __device__ __forceinline__ unsigned short f32_to_bf16(float f) {
    unsigned int u = __float_as_uint(f);
    unsigned int r = u + 0x7FFFu + ((u >> 16) & 1u);   // RNE
    return (unsigned short)(r >> 16);
}
static __device__ __forceinline__ float bflo(unsigned int u) {
    return __uint_as_float(u << 16);
}
static __device__ __forceinline__ float bfhi(unsigned int u) {
    return __uint_as_float(u & 0xFFFF0000u);
}

// ---------------- merged prep: wct1 | wct2 | x->bf16 | bucket count ----------------

static __device__ __forceinline__ void prepw_body(const float* __restrict__ W,
                                                  const float* __restrict__ Root,
                                                  unsigned short* __restrict__ WcT,
                                                  int i) {
    if (i >= 64 * KTOT) return;
    int o = i / KTOT;
    int k = i - o * KTOT;
    float v;
    if (k < 512) v = W[(size_t)(k >> 6) * 4096 + (k & 63) * 64 + o];
    else         v = Root[(k - 512) * 64 + o];
    WcT[(size_t)o * KTOT + k] = f32_to_bf16(v);
}

__global__ void k_prep(const float* __restrict__ w1, const float* __restrict__ root1,
                       const float* __restrict__ w2, const float* __restrict__ root2,
                       unsigned short* __restrict__ wct1, unsigned short* __restrict__ wct2,
                       const float* __restrict__ X, unsigned short* __restrict__ Xb,
                       const int* __restrict__ dst, int* __restrict__ btot) {
    __shared__ int cnt[NB];
    int b = blockIdx.x;
    int t = threadIdx.x;
    if (b < PREPW_BLKS) {
        prepw_body(w1, root1, wct1, b * 256 + t);
    } else if (b < 2 * PREPW_BLKS) {
        prepw_body(w2, root2, wct2, (b - PREPW_BLKS) * 256 + t);
    } else if (b < 2 * PREPW_BLKS + TOBF_BLKS) {
        int i = (b - 2 * PREPW_BLKS) * 256 + t;
        float4 v = ((const float4*)X)[i];
        ushort4 o;
        o.x = f32_to_bf16(v.x); o.y = f32_to_bf16(v.y);
        o.z = f32_to_bf16(v.z); o.w = f32_to_bf16(v.w);
        ((ushort4*)Xb)[i] = o;
    } else {
        int bb = b - (2 * PREPW_BLKS + TOBF_BLKS);
        for (int i = t; i < NB; i += 256) cnt[i] = 0;
        __syncthreads();
        int base = bb * EPB;
#pragma unroll
        for (int i = 0; i < EPB / 256; ++i) {
            int e = base + i * 256 + t;
            if (e < EE) atomicAdd(&cnt[dst[e] >> 8], 1);
        }
        __syncthreads();
        for (int i = t; i < NB; i += 256)
            if (cnt[i]) atomicAdd(&btot[i], cnt[i]);
    }
}

__global__ void k_bscan(const int* __restrict__ btot, int* __restrict__ bbase,
                        int* __restrict__ gcur, int* __restrict__ rowptr) {
    __shared__ int sd[512];
    int t = threadIdx.x;
    int v = (t < NB) ? btot[t] : 0;
    sd[t] = v;
    __syncthreads();
    for (int off = 1; off < 512; off <<= 1) {
        int x = (t >= off) ? sd[t - off] : 0;
        __syncthreads();
        sd[t] += x;
        __syncthreads();
    }
    if (t < NB) { bbase[t] = sd[t] - v; gcur[t] = sd[t] - v; }
    if (t == NB - 1) { bbase[NB] = sd[t]; rowptr[MM] = sd[t]; }
}

// bin edges into bucket-contiguous ebuf, packed: src | (localkey << 17)
__global__ void k_bin(const int* __restrict__ src, const int* __restrict__ dst,
                      const int* __restrict__ et, int* __restrict__ gcur,
                      unsigned int* __restrict__ ebuf) {
    __shared__ int cnt[NB];
    __shared__ int bas[NB];
    __shared__ int off[NB];
    int t = threadIdx.x;
    for (int i = t; i < NB; i += 256) { cnt[i] = 0; off[i] = 0; }
    __syncthreads();
    int base = blockIdx.x * EPB;
#pragma unroll
    for (int i = 0; i < EPB / 256; ++i) {
        int e = base + i * 256 + t;
        if (e < EE) atomicAdd(&cnt[dst[e] >> 8], 1);
    }
    __syncthreads();
    for (int i = t; i < NB; i += 256) {
        int c = cnt[i];
        bas[i] = c ? atomicAdd(&gcur[i], c) : 0;
    }
    __syncthreads();
#pragma unroll
    for (int i = 0; i < EPB / 256; ++i) {
        int e = base + i * 256 + t;
        if (e < EE) {
            int d = dst[e];
            int b = d >> 8;
            int lk = ((d & 255) << 3) | et[e];
            unsigned int rec0 = (unsigned int)src[e] | ((unsigned int)lk << 17);
            int p = bas[b] + atomicAdd(&off[b], 1);
            ebuf[p] = rec0;
        }
    }
}

// per-bucket: LDS histogram + scan -> rowptr; LDS cursors -> sorted rec
__global__ __launch_bounds__(256) void k_bcsr(const int* __restrict__ bbase,
                                              const unsigned int* __restrict__ ebuf,
                                              int* __restrict__ rowptr,
                                              int* __restrict__ rec) {
    __shared__ int deg[2048];
    __shared__ int part[256];
    int b = blockIdx.x, t = threadIdx.x;
    int e0 = bbase[b], e1 = bbase[b + 1];
    for (int i = t; i < 2048; i += 256) deg[i] = 0;
    __syncthreads();
    for (int e = e0 + t; e < e1; e += 256) atomicAdd(&deg[ebuf[e] >> 17], 1);
    __syncthreads();
    int loc[8];
    int s = 0;
#pragma unroll
    for (int j = 0; j < 8; ++j) { loc[j] = deg[t * 8 + j]; s += loc[j]; }
    part[t] = s;
    __syncthreads();
    for (int off = 1; off < 256; off <<= 1) {
        int x = (t >= off) ? part[t - off] : 0;
        __syncthreads();
        part[t] += x;
        __syncthreads();
    }
    int run = part[t] - s;
    int keyBase = b * 2048;
#pragma unroll
    for (int j = 0; j < 8; ++j) {
        int g = keyBase + t * 8 + j;
        if (g < MM) rowptr[g] = e0 + run;
        deg[t * 8 + j] = run;
        run += loc[j];
    }
    __syncthreads();
    for (int e = e0 + t; e < e1; e += 256) {
        unsigned int v = ebuf[e];
        int lk = v >> 17;
        int pos = e0 + atomicAdd(&deg[lk], 1);
        rec[pos] = (int)(v & 0x1FFFFu);
    }
}

// ---------------- fused aggregation + MFMA GEMM ----------------
// Block = 1024 threads = 16 waves = 16 nodes, ONE WAVE PER NODE (agg TLP
// matches the round-7 standalone k_agg). Wave wv aggregates node n0+wv into
// LDS As[wv][584] (512 mean + 64 own-Xb tail, bf16). Barrier. Waves 0..3
// each compute a 16x16 output col-tile over K=576 (A: LDS, B: WcT from
// global, L2-hot). Fused BN column stats.

__global__ __launch_bounds__(1024, 8) void k_aggemm(const unsigned short* __restrict__ Xb,
                                                    const int* __restrict__ rowptr,
                                                    const int* __restrict__ rec,
                                                    const unsigned short* __restrict__ WcT,
                                                    const float* __restrict__ bias,
                                                    float* __restrict__ Out,
                                                    float* __restrict__ stats,
                                                    int dostats) {
    __shared__ unsigned short As[16 * APITCH];   // 18.25 KB
    int t = threadIdx.x;
    int wv = t >> 6, lane = t & 63;
    int n0 = blockIdx.x * 16;
    int n = n0 + wv;
    int r = lane >> 3;       // segment 0..7
    int q = lane & 7;        // dim-octet 0..7

    int e0 = rowptr[n * RR + r];
    int e1 = rowptr[n * RR + r + 1];
    float a0[8] = {0,0,0,0,0,0,0,0};
    float a1[8] = {0,0,0,0,0,0,0,0};
    float a2[8] = {0,0,0,0,0,0,0,0};
    float a3[8] = {0,0,0,0,0,0,0,0};
    int e = e0;
    for (; e + 3 < e1; e += 4) {
        int s0 = rec[e], s1 = rec[e + 1], s2 = rec[e + 2], s3 = rec[e + 3];
        uint4 u0 = *(const uint4*)(Xb + (size_t)s0 * DD + q * 8);
        uint4 u1 = *(const uint4*)(Xb + (size_t)s1 * DD + q * 8);
        uint4 u2 = *(const uint4*)(Xb + (size_t)s2 * DD + q * 8);
        uint4 u3 = *(const uint4*)(Xb + (size_t)s3 * DD + q * 8);
        a0[0] += bflo(u0.x); a0[1] += bfhi(u0.x); a0[2] += bflo(u0.y); a0[3] += bfhi(u0.y);
        a0[4] += bflo(u0.z); a0[5] += bfhi(u0.z); a0[6] += bflo(u0.w); a0[7] += bfhi(u0.w);
        a1[0] += bflo(u1.x); a1[1] += bfhi(u1.x); a1[2] += bflo(u1.y); a1[3] += bfhi(u1.y);
        a1[4] += bflo(u1.z); a1[5] += bfhi(u1.z); a1[6] += bflo(u1.w); a1[7] += bfhi(u1.w);
        a2[0] += bflo(u2.x); a2[1] += bfhi(u2.x); a2[2] += bflo(u2.y); a2[3] += bfhi(u2.y);
        a2[4] += bflo(u2.z); a2[5] += bfhi(u2.z); a2[6] += bflo(u2.w); a2[7] += bfhi(u2.w);
        a3[0] += bflo(u3.x); a3[1] += bfhi(u3.x); a3[2] += bflo(u3.y); a3[3] += bfhi(u3.y);
        a3[4] += bflo(u3.z); a3[5] += bfhi(u3.z); a3[6] += bflo(u3.w); a3[7] += bfhi(u3.w);
    }
    if (e + 1 < e1) {
        int s0 = rec[e], s1 = rec[e + 1];
        uint4 u0 = *(const uint4*)(Xb + (size_t)s0 * DD + q * 8);
        uint4 u1 = *(const uint4*)(Xb + (size_t)s1 * DD + q * 8);
        a0[0] += bflo(u0.x); a0[1] += bfhi(u0.x); a0[2] += bflo(u0.y); a0[3] += bfhi(u0.y);
        a0[4] += bflo(u0.z); a0[5] += bfhi(u0.z); a0[6] += bflo(u0.w); a0[7] += bfhi(u0.w);
        a1[0] += bflo(u1.x); a1[1] += bfhi(u1.x); a1[2] += bflo(u1.y); a1[3] += bfhi(u1.y);
        a1[4] += bflo(u1.z); a1[5] += bfhi(u1.z); a1[6] += bflo(u1.w); a1[7] += bfhi(u1.w);
        e += 2;
    }
    if (e < e1) {
        int s0 = rec[e];
        uint4 u0 = *(const uint4*)(Xb + (size_t)s0 * DD + q * 8);
        a0[0] += bflo(u0.x); a0[1] += bfhi(u0.x); a0[2] += bflo(u0.y); a0[3] += bfhi(u0.y);
        a0[4] += bflo(u0.z); a0[5] += bfhi(u0.z); a0[6] += bflo(u0.w); a0[7] += bfhi(u0.w);
    }
    int cnt = e1 - e0;
    float inv = 1.0f / (float)(cnt > 1 ? cnt : 1);
    uint4 o;
    o.x = (unsigned)f32_to_bf16((a0[0]+a1[0]+a2[0]+a3[0]) * inv) | ((unsigned)f32_to_bf16((a0[1]+a1[1]+a2[1]+a3[1]) * inv) << 16);
    o.y = (unsigned)f32_to_bf16((a0[2]+a1[2]+a2[2]+a3[2]) * inv) | ((unsigned)f32_to_bf16((a0[3]+a1[3]+a2[3]+a3[3]) * inv) << 16);
    o.z = (unsigned)f32_to_bf16((a0[4]+a1[4]+a2[4]+a3[4]) * inv) | ((unsigned)f32_to_bf16((a0[5]+a1[5]+a2[5]+a3[5]) * inv) << 16);
    o.w = (unsigned)f32_to_bf16((a0[6]+a1[6]+a2[6]+a3[6]) * inv) | ((unsigned)f32_to_bf16((a0[7]+a1[7]+a2[7]+a3[7]) * inv) << 16);
    *(uint4*)(As + wv * APITCH + r * 64 + q * 8) = o;
    if (r == 0) {   // K-tail: node's own Xb row (root term)
        uint4 xo = *(const uint4*)(Xb + (size_t)n * DD + q * 8);
        *(uint4*)(As + wv * APITCH + 512 + q * 8) = xo;
    }
    __syncthreads();

    // GEMM phase: waves 0..3 -> output cols wv*16..+15, rows = block's 16 nodes
    if (wv < 4) {
        int quad = lane >> 4, m16 = lane & 15;
        union AU { uint4 u; bf16x8 f; };
        f32x4 acc = {0.f, 0.f, 0.f, 0.f};
        const unsigned short* ap = As + m16 * APITCH + quad * 8;
        const unsigned short* wp = WcT + (size_t)(wv * 16 + m16) * KTOT + quad * 8;
#pragma unroll
        for (int kb = 0; kb < 18; ++kb) {
            AU a, b;
            a.u = *(const uint4*)(ap + kb * 32);
            b.u = *(const uint4*)(wp + kb * 32);
            acc = __builtin_amdgcn_mfma_f32_16x16x32_bf16(a.f, b.f, acc, 0, 0, 0);
        }
        int col = wv * 16 + m16;
        float bb = bias[col];
        float s = 0.f, sq = 0.f;
#pragma unroll
        for (int i = 0; i < 4; ++i) {
            int row = quad * 4 + i;
            float v = acc[i] + bb;
            Out[(size_t)(n0 + row) * 64 + col] = v;
            s += v; sq += v * v;
        }
        if (dostats) {
            s += __shfl_xor(s, 16); s += __shfl_xor(s, 32);
            sq += __shfl_xor(sq, 16); sq += __shfl_xor(sq, 32);
            if (quad == 0) {
                atomicAdd(&stats[col], s);
                atomicAdd(&stats[64 + col], sq);
            }
        }
    }
}

// ---------------- BN+ReLU (in-place, + bf16 copy) ----------------

__global__ void k_bnrelu(float* __restrict__ H, unsigned short* __restrict__ Hb,
                         const float* __restrict__ stats,
                         const float* __restrict__ gamma, const float* __restrict__ beta) {
    int idx = blockIdx.x * 256 + threadIdx.x;
    const int total = NN * DD / 4;
    if (idx >= total) return;
    int c0 = (idx & 15) * 4;
    float4 v = ((const float4*)H)[idx];
    float inv = 1.0f / (float)NN;
    float4 o;
    {
        float mu = stats[c0 + 0] * inv;
        float var = stats[64 + c0 + 0] * inv - mu * mu;
        float sc = gamma[c0 + 0] * rsqrtf(var + BN_EPS);
        float r = sc * (v.x - mu) + beta[c0 + 0];
        o.x = r > 0.f ? r : 0.f;
    }
    {
        float mu = stats[c0 + 1] * inv;
        float var = stats[64 + c0 + 1] * inv - mu * mu;
        float sc = gamma[c0 + 1] * rsqrtf(var + BN_EPS);
        float r = sc * (v.y - mu) + beta[c0 + 1];
        o.y = r > 0.f ? r : 0.f;
    }
    {
        float mu = stats[c0 + 2] * inv;
        float var = stats[64 + c0 + 2] * inv - mu * mu;
        float sc = gamma[c0 + 2] * rsqrtf(var + BN_EPS);
        float r = sc * (v.z - mu) + beta[c0 + 2];
        o.z = r > 0.f ? r : 0.f;
    }
    {
        float mu = stats[c0 + 3] * inv;
        float var = stats[64 + c0 + 3] * inv - mu * mu;
        float sc = gamma[c0 + 3] * rsqrtf(var + BN_EPS);
        float r = sc * (v.w - mu) + beta[c0 + 3];
        o.w = r > 0.f ? r : 0.f;
    }
    ((float4*)H)[idx] = o;
    ushort4 ob;
    ob.x = f32_to_bf16(o.x); ob.y = f32_to_bf16(o.y);
    ob.z = f32_to_bf16(o.z); ob.w = f32_to_bf16(o.w);
    ((ushort4*)Hb)[idx] = ob;
}

// ---------------- launch ----------------

static inline size_t alignup(size_t x) { return (x + 255) & ~(size_t)255; }

extern "C" void kernel_launch(void* const* d_in, const int* in_sizes, int n_in,
                              void* d_out, int out_size, void* d_ws, size_t ws_size,
                              hipStream_t stream) {
    const float* x      = (const float*)d_in[0];
    const int*   eidx   = (const int*)d_in[1];
    const int*   etype  = (const int*)d_in[2];
    const float* w1     = (const float*)d_in[3];
    const float* root1  = (const float*)d_in[4];
    const float* b1     = (const float*)d_in[5];
    const float* gamma1 = (const float*)d_in[6];
    const float* beta1  = (const float*)d_in[7];
    const float* w2     = (const float*)d_in[8];
    const float* root2  = (const float*)d_in[9];
    const float* b2     = (const float*)d_in[10];
    float* out = (float*)d_out;

    const int* src = eidx;
    const int* dst = eidx + EE;

    char* w = (char*)d_ws;
    int* rowptr = (int*)w;            w += alignup((size_t)(MM + 1) * 4);
    int* btot   = (int*)w;            w += alignup(512 * 4);
    int* bbase  = (int*)w;            w += alignup(512 * 4);
    int* gcur   = (int*)w;            w += alignup(512 * 4);
    int* rec    = (int*)w;            w += alignup((size_t)EE * 4);
    unsigned int* ebuf = (unsigned int*)w; w += alignup((size_t)EE * 4);
    float* h    = (float*)w;          w += alignup((size_t)NN * DD * 4);
    unsigned short* xhb = (unsigned short*)w; w += alignup((size_t)NN * DD * 2);
    unsigned short* wct1 = (unsigned short*)w; w += alignup((size_t)64 * KTOT * 2);
    unsigned short* wct2 = (unsigned short*)w; w += alignup((size_t)64 * KTOT * 2);
    float* stats = (float*)w;         w += alignup(128 * 4);

    hipMemsetAsync(btot, 0, 512 * 4, stream);
    hipMemsetAsync(stats, 0, 128 * 4, stream);

    // merged prep: wct1 | wct2 | tobf16 | bucket-count
    k_prep<<<dim3(2 * PREPW_BLKS + TOBF_BLKS + NBIN), dim3(256), 0, stream>>>(
        w1, root1, w2, root2, wct1, wct2, x, xhb, dst, btot);

    k_bscan<<<dim3(1), dim3(512), 0, stream>>>(btot, bbase, gcur, rowptr);
    k_bin<<<dim3(NBIN), dim3(256), 0, stream>>>(src, dst, etype, gcur, ebuf);
    k_bcsr<<<dim3(NB), dim3(256), 0, stream>>>(bbase, ebuf, rowptr, rec);

    // layer 1 (fused agg + gemm + BN column stats), one wave per node
    k_aggemm<<<dim3(NN / 16), dim3(1024), 0, stream>>>(xhb, rowptr, rec, wct1, b1, h, stats, 1);
    k_bnrelu<<<dim3(NN * DD / 4 / 256), dim3(256), 0, stream>>>(h, xhb, stats, gamma1, beta1);

    // layer 2 (xhb now holds bf16 of post-BN/ReLU h)
    k_aggemm<<<dim3(NN / 16), dim3(1024), 0, stream>>>(xhb, rowptr, rec, wct2, b2, out, stats, 0);
}

// Round 10
// 390.998 us; speedup vs baseline: 1.2176x; 1.1516x over previous
//
#include <hip/hip_runtime.h>
#include <hip/hip_bf16.h>

#define NN 100000
#define EE 1600000
#define RR 8
#define DD 64
#define MM (NN * RR)                 // 800000 (dst,rel) segments
#define BN_EPS 1e-5f
#define KTOT 576                     // 512 (rel) + 64 (root)
#define BSTRIDE 584                  // LDS B row pitch in shorts (292 words % 32 = 4)

// bucket sort params: 256 dsts per bucket -> 2048 (dst,rel) keys per bucket
#define NB 391                       // ceil(100000/256)
#define EPB 8192                     // edges per block in binning kernels
#define NBIN ((EE + EPB - 1) / EPB)  // 196

// merged prep kernel grid sections
#define PREPW_BLKS 144               // ceil(64*576/256)
#define TOBF_BLKS (NN * DD / 4 / 256)  // 6250

// persistent-wave agg grid
#define AGG_BLKS 2048                // 8192 waves = 32/CU

typedef __bf16 bf16x8 __attribute__((ext_vector_type(8)));
typedef float  f32x4  __attribute__((ext_vector_type(4)));

static __device__ __forceinline__ unsigned short f32_to_bf16(float f) {
    unsigned int u = __float_as_uint(f);
    unsigned int r = u + 0x7FFFu + ((u >> 16) & 1u);   // RNE
    return (unsigned short)(r >> 16);
}
static __device__ __forceinline__ float bflo(unsigned int u) {
    return __uint_as_float(u << 16);
}
static __device__ __forceinline__ float bfhi(unsigned int u) {
    return __uint_as_float(u & 0xFFFF0000u);
}

// ---------------- merged prep: wct1 | wct2 | x->bf16 | bucket count ----------------

static __device__ __forceinline__ void prepw_body(const float* __restrict__ W,
                                                  const float* __restrict__ Root,
                                                  unsigned short* __restrict__ WcT,
                                                  int i) {
    if (i >= 64 * KTOT) return;
    int o = i / KTOT;
    int k = i - o * KTOT;
    float v;
    if (k < 512) v = W[(size_t)(k >> 6) * 4096 + (k & 63) * 64 + o];
    else         v = Root[(k - 512) * 64 + o];
    WcT[(size_t)o * KTOT + k] = f32_to_bf16(v);
}

__global__ void k_prep(const float* __restrict__ w1, const float* __restrict__ root1,
                       const float* __restrict__ w2, const float* __restrict__ root2,
                       unsigned short* __restrict__ wct1, unsigned short* __restrict__ wct2,
                       const float* __restrict__ X, unsigned short* __restrict__ Xb,
                       const int* __restrict__ dst, int* __restrict__ btot) {
    __shared__ int cnt[NB];
    int b = blockIdx.x;
    int t = threadIdx.x;
    if (b < PREPW_BLKS) {
        prepw_body(w1, root1, wct1, b * 256 + t);
    } else if (b < 2 * PREPW_BLKS) {
        prepw_body(w2, root2, wct2, (b - PREPW_BLKS) * 256 + t);
    } else if (b < 2 * PREPW_BLKS + TOBF_BLKS) {
        int i = (b - 2 * PREPW_BLKS) * 256 + t;
        float4 v = ((const float4*)X)[i];
        ushort4 o;
        o.x = f32_to_bf16(v.x); o.y = f32_to_bf16(v.y);
        o.z = f32_to_bf16(v.z); o.w = f32_to_bf16(v.w);
        ((ushort4*)Xb)[i] = o;
    } else {
        int bb = b - (2 * PREPW_BLKS + TOBF_BLKS);
        for (int i = t; i < NB; i += 256) cnt[i] = 0;
        __syncthreads();
        int base = bb * EPB;
#pragma unroll
        for (int i = 0; i < EPB / 256; ++i) {
            int e = base + i * 256 + t;
            if (e < EE) atomicAdd(&cnt[dst[e] >> 8], 1);
        }
        __syncthreads();
        for (int i = t; i < NB; i += 256)
            if (cnt[i]) atomicAdd(&btot[i], cnt[i]);
    }
}

__global__ void k_bscan(const int* __restrict__ btot, int* __restrict__ bbase,
                        int* __restrict__ gcur, int* __restrict__ rowptr) {
    __shared__ int sd[512];
    int t = threadIdx.x;
    int v = (t < NB) ? btot[t] : 0;
    sd[t] = v;
    __syncthreads();
    for (int off = 1; off < 512; off <<= 1) {
        int x = (t >= off) ? sd[t - off] : 0;
        __syncthreads();
        sd[t] += x;
        __syncthreads();
    }
    if (t < NB) { bbase[t] = sd[t] - v; gcur[t] = sd[t] - v; }
    if (t == NB - 1) { bbase[NB] = sd[t]; rowptr[MM] = sd[t]; }
}

// bin edges into bucket-contiguous ebuf, packed: src | (localkey << 17)
__global__ void k_bin(const int* __restrict__ src, const int* __restrict__ dst,
                      const int* __restrict__ et, int* __restrict__ gcur,
                      unsigned int* __restrict__ ebuf) {
    __shared__ int cnt[NB];
    __shared__ int bas[NB];
    __shared__ int off[NB];
    int t = threadIdx.x;
    for (int i = t; i < NB; i += 256) { cnt[i] = 0; off[i] = 0; }
    __syncthreads();
    int base = blockIdx.x * EPB;
#pragma unroll
    for (int i = 0; i < EPB / 256; ++i) {
        int e = base + i * 256 + t;
        if (e < EE) atomicAdd(&cnt[dst[e] >> 8], 1);
    }
    __syncthreads();
    for (int i = t; i < NB; i += 256) {
        int c = cnt[i];
        bas[i] = c ? atomicAdd(&gcur[i], c) : 0;
    }
    __syncthreads();
#pragma unroll
    for (int i = 0; i < EPB / 256; ++i) {
        int e = base + i * 256 + t;
        if (e < EE) {
            int d = dst[e];
            int b = d >> 8;
            int lk = ((d & 255) << 3) | et[e];
            unsigned int rec0 = (unsigned int)src[e] | ((unsigned int)lk << 17);
            int p = bas[b] + atomicAdd(&off[b], 1);
            ebuf[p] = rec0;
        }
    }
}

// per-bucket: LDS histogram + scan -> rowptr; LDS cursors -> sorted rec
__global__ __launch_bounds__(256) void k_bcsr(const int* __restrict__ bbase,
                                              const unsigned int* __restrict__ ebuf,
                                              int* __restrict__ rowptr,
                                              int* __restrict__ rec) {
    __shared__ int deg[2048];
    __shared__ int part[256];
    int b = blockIdx.x, t = threadIdx.x;
    int e0 = bbase[b], e1 = bbase[b + 1];
    for (int i = t; i < 2048; i += 256) deg[i] = 0;
    __syncthreads();
    for (int e = e0 + t; e < e1; e += 256) atomicAdd(&deg[ebuf[e] >> 17], 1);
    __syncthreads();
    int loc[8];
    int s = 0;
#pragma unroll
    for (int j = 0; j < 8; ++j) { loc[j] = deg[t * 8 + j]; s += loc[j]; }
    part[t] = s;
    __syncthreads();
    for (int off = 1; off < 256; off <<= 1) {
        int x = (t >= off) ? part[t - off] : 0;
        __syncthreads();
        part[t] += x;
        __syncthreads();
    }
    int run = part[t] - s;
    int keyBase = b * 2048;
#pragma unroll
    for (int j = 0; j < 8; ++j) {
        int g = keyBase + t * 8 + j;
        if (g < MM) rowptr[g] = e0 + run;
        deg[t * 8 + j] = run;
        run += loc[j];
    }
    __syncthreads();
    for (int e = e0 + t; e < e1; e += 256) {
        unsigned int v = ebuf[e];
        int lk = v >> 17;
        int pos = e0 + atomicAdd(&deg[lk], 1);
        rec[pos] = (int)(v & 0x1FFFFu);
    }
}

// ---------------- aggregation: persistent waves, one node per wave-iteration ----------------
// mean layout: [N][512] bf16, k = r*64 + d. 8 lanes per (dst,rel) segment,
// edge loop unrolled x4 for MLP. Grid-stride keeps occupancy pinned.

__global__ __launch_bounds__(256) void k_agg(const unsigned short* __restrict__ Xb,
                                             const int* __restrict__ rowptr,
                                             const int* __restrict__ rec,
                                             unsigned short* __restrict__ mean) {
    int wv = threadIdx.x >> 6;
    int lane = threadIdx.x & 63;
    int r = lane >> 3;       // segment 0..7
    int q = lane & 7;        // dim-octet 0..7
    int stride = gridDim.x * 4;
#pragma unroll 1
    for (int n = blockIdx.x * 4 + wv; n < NN; n += stride) {
        int e0 = rowptr[n * RR + r];
        int e1 = rowptr[n * RR + r + 1];
        float a0[8] = {0,0,0,0,0,0,0,0};
        float a1[8] = {0,0,0,0,0,0,0,0};
        float a2[8] = {0,0,0,0,0,0,0,0};
        float a3[8] = {0,0,0,0,0,0,0,0};
        int e = e0;
        for (; e + 3 < e1; e += 4) {
            int s0 = rec[e], s1 = rec[e + 1], s2 = rec[e + 2], s3 = rec[e + 3];
            uint4 u0 = *(const uint4*)(Xb + (size_t)s0 * DD + q * 8);
            uint4 u1 = *(const uint4*)(Xb + (size_t)s1 * DD + q * 8);
            uint4 u2 = *(const uint4*)(Xb + (size_t)s2 * DD + q * 8);
            uint4 u3 = *(const uint4*)(Xb + (size_t)s3 * DD + q * 8);
            a0[0] += bflo(u0.x); a0[1] += bfhi(u0.x); a0[2] += bflo(u0.y); a0[3] += bfhi(u0.y);
            a0[4] += bflo(u0.z); a0[5] += bfhi(u0.z); a0[6] += bflo(u0.w); a0[7] += bfhi(u0.w);
            a1[0] += bflo(u1.x); a1[1] += bfhi(u1.x); a1[2] += bflo(u1.y); a1[3] += bfhi(u1.y);
            a1[4] += bflo(u1.z); a1[5] += bfhi(u1.z); a1[6] += bflo(u1.w); a1[7] += bfhi(u1.w);
            a2[0] += bflo(u2.x); a2[1] += bfhi(u2.x); a2[2] += bflo(u2.y); a2[3] += bfhi(u2.y);
            a2[4] += bflo(u2.z); a2[5] += bfhi(u2.z); a2[6] += bflo(u2.w); a2[7] += bfhi(u2.w);
            a3[0] += bflo(u3.x); a3[1] += bfhi(u3.x); a3[2] += bflo(u3.y); a3[3] += bfhi(u3.y);
            a3[4] += bflo(u3.z); a3[5] += bfhi(u3.z); a3[6] += bflo(u3.w); a3[7] += bfhi(u3.w);
        }
        if (e + 1 < e1) {
            int s0 = rec[e], s1 = rec[e + 1];
            uint4 u0 = *(const uint4*)(Xb + (size_t)s0 * DD + q * 8);
            uint4 u1 = *(const uint4*)(Xb + (size_t)s1 * DD + q * 8);
            a0[0] += bflo(u0.x); a0[1] += bfhi(u0.x); a0[2] += bflo(u0.y); a0[3] += bfhi(u0.y);
            a0[4] += bflo(u0.z); a0[5] += bfhi(u0.z); a0[6] += bflo(u0.w); a0[7] += bfhi(u0.w);
            a1[0] += bflo(u1.x); a1[1] += bfhi(u1.x); a1[2] += bflo(u1.y); a1[3] += bfhi(u1.y);
            a1[4] += bflo(u1.z); a1[5] += bfhi(u1.z); a1[6] += bflo(u1.w); a1[7] += bfhi(u1.w);
            e += 2;
        }
        if (e < e1) {
            int s0 = rec[e];
            uint4 u0 = *(const uint4*)(Xb + (size_t)s0 * DD + q * 8);
            a0[0] += bflo(u0.x); a0[1] += bfhi(u0.x); a0[2] += bflo(u0.y); a0[3] += bfhi(u0.y);
            a0[4] += bflo(u0.z); a0[5] += bfhi(u0.z); a0[6] += bflo(u0.w); a0[7] += bfhi(u0.w);
        }
        int cnt = e1 - e0;
        float inv = 1.0f / (float)(cnt > 1 ? cnt : 1);
        uint4 o;
        o.x = (unsigned)f32_to_bf16((a0[0]+a1[0]+a2[0]+a3[0]) * inv) | ((unsigned)f32_to_bf16((a0[1]+a1[1]+a2[1]+a3[1]) * inv) << 16);
        o.y = (unsigned)f32_to_bf16((a0[2]+a1[2]+a2[2]+a3[2]) * inv) | ((unsigned)f32_to_bf16((a0[3]+a1[3]+a2[3]+a3[3]) * inv) << 16);
        o.z = (unsigned)f32_to_bf16((a0[4]+a1[4]+a2[4]+a3[4]) * inv) | ((unsigned)f32_to_bf16((a0[5]+a1[5]+a2[5]+a3[5]) * inv) << 16);
        o.w = (unsigned)f32_to_bf16((a0[6]+a1[6]+a2[6]+a3[6]) * inv) | ((unsigned)f32_to_bf16((a0[7]+a1[7]+a2[7]+a3[7]) * inv) << 16);
        *(uint4*)(mean + (size_t)n * 512 + r * 64 + q * 8) = o;
    }
}

// ---------------- MFMA GEMM: out[N][64] = [mean | Xb] @ Wc + bias ----------------
// B (WcT) staged in LDS (padded stride). Wave: 32 rows x 64 cols.
// Optional fused column-stats (sum, sumsq) for BN.

__global__ __launch_bounds__(256) void k_gemm(const unsigned short* __restrict__ meanB,
                                              const unsigned short* __restrict__ Xb,
                                              const unsigned short* __restrict__ WcT,
                                              const float* __restrict__ bias,
                                              float* __restrict__ Out,
                                              float* __restrict__ stats,
                                              int dostats) {
    __shared__ unsigned short Bs[64 * BSTRIDE];   // 73 KB
    __shared__ float ssum[4][64];
    __shared__ float ssq[4][64];
    int t = threadIdx.x;
    // stage WcT -> Bs: 64 rows x 72 uint4 chunks = 4608 chunks
#pragma unroll
    for (int i = 0; i < 18; ++i) {
        int idx = i * 256 + t;
        int row = idx / 72;
        int k16 = idx - row * 72;
        uint4 v = *(const uint4*)(WcT + (size_t)row * KTOT + k16 * 8);
        *(uint4*)(Bs + row * BSTRIDE + k16 * 8) = v;
    }
    __syncthreads();

    int wv = t >> 6, lane = t & 63;
    int quad = lane >> 4, m16 = lane & 15;
    int row0 = blockIdx.x * 128 + wv * 32;
    int r0 = row0 + m16;
    int r1 = row0 + 16 + m16;
    bool ok0 = r0 < NN, ok1 = r1 < NN;

    union AU { uint4 u; bf16x8 f; };
    f32x4 acc[2][4];
#pragma unroll
    for (int i = 0; i < 2; ++i)
#pragma unroll
        for (int j = 0; j < 4; ++j) acc[i][j] = (f32x4){0.f, 0.f, 0.f, 0.f};

    const unsigned short* a0p = meanB + (size_t)r0 * 512 + quad * 8;
    const unsigned short* a1p = meanB + (size_t)r1 * 512 + quad * 8;
    const unsigned short* x0p = Xb + (size_t)r0 * DD + quad * 8;
    const unsigned short* x1p = Xb + (size_t)r1 * DD + quad * 8;
    const unsigned short* bs  = Bs + m16 * BSTRIDE + quad * 8;

#pragma unroll
    for (int kb = 0; kb < 16; ++kb) {
        AU av0, av1, bv[4];
        if (ok0) av0.u = *(const uint4*)(a0p + kb * 32); else av0.u = make_uint4(0,0,0,0);
        if (ok1) av1.u = *(const uint4*)(a1p + kb * 32); else av1.u = make_uint4(0,0,0,0);
#pragma unroll
        for (int nt = 0; nt < 4; ++nt)
            bv[nt].u = *(const uint4*)(bs + nt * 16 * BSTRIDE + kb * 32);
#pragma unroll
        for (int nt = 0; nt < 4; ++nt) {
            acc[0][nt] = __builtin_amdgcn_mfma_f32_16x16x32_bf16(av0.f, bv[nt].f, acc[0][nt], 0, 0, 0);
            acc[1][nt] = __builtin_amdgcn_mfma_f32_16x16x32_bf16(av1.f, bv[nt].f, acc[1][nt], 0, 0, 0);
        }
    }
#pragma unroll
    for (int kb = 0; kb < 2; ++kb) {
        AU av0, av1, bv[4];
        if (ok0) av0.u = *(const uint4*)(x0p + kb * 32); else av0.u = make_uint4(0,0,0,0);
        if (ok1) av1.u = *(const uint4*)(x1p + kb * 32); else av1.u = make_uint4(0,0,0,0);
#pragma unroll
        for (int nt = 0; nt < 4; ++nt)
            bv[nt].u = *(const uint4*)(bs + nt * 16 * BSTRIDE + 512 + kb * 32);
#pragma unroll
        for (int nt = 0; nt < 4; ++nt) {
            acc[0][nt] = __builtin_amdgcn_mfma_f32_16x16x32_bf16(av0.f, bv[nt].f, acc[0][nt], 0, 0, 0);
            acc[1][nt] = __builtin_amdgcn_mfma_f32_16x16x32_bf16(av1.f, bv[nt].f, acc[1][nt], 0, 0, 0);
        }
    }

#pragma unroll
    for (int rt = 0; rt < 2; ++rt) {
#pragma unroll
        for (int nt = 0; nt < 4; ++nt) {
            int col = nt * 16 + m16;
            float bb = bias[col];
#pragma unroll
            for (int i = 0; i < 4; ++i) {
                int row = row0 + rt * 16 + quad * 4 + i;
                if (row < NN) Out[(size_t)row * 64 + col] = acc[rt][nt][i] + bb;
            }
        }
    }

    if (dostats) {
#pragma unroll
        for (int nt = 0; nt < 4; ++nt) {
            int col = nt * 16 + m16;
            float bb = bias[col];
            float s = 0.f, sq = 0.f;
#pragma unroll
            for (int rt = 0; rt < 2; ++rt) {
#pragma unroll
                for (int i = 0; i < 4; ++i) {
                    int row = row0 + rt * 16 + quad * 4 + i;
                    if (row < NN) {
                        float v = acc[rt][nt][i] + bb;
                        s += v; sq += v * v;
                    }
                }
            }
            s += __shfl_xor(s, 16); s += __shfl_xor(s, 32);
            sq += __shfl_xor(sq, 16); sq += __shfl_xor(sq, 32);
            if (quad == 0) { ssum[wv][col] = s; ssq[wv][col] = sq; }
        }
        __syncthreads();
        if (t < 128) {
            int col = t & 63;
            if (t < 64) {
                float s = ssum[0][col] + ssum[1][col] + ssum[2][col] + ssum[3][col];
                atomicAdd(&stats[col], s);
            } else {
                float sq = ssq[0][col] + ssq[1][col] + ssq[2][col] + ssq[3][col];
                atomicAdd(&stats[64 + col], sq);
            }
        }
    }
}

// ---------------- BN+ReLU (in-place, + bf16 copy) ----------------

__global__ void k_bnrelu(float* __restrict__ H, unsigned short* __restrict__ Hb,
                         const float* __restrict__ stats,
                         const float* __restrict__ gamma, const float* __restrict__ beta) {
    int idx = blockIdx.x * 256 + threadIdx.x;
    const int total = NN * DD / 4;
    if (idx >= total) return;
    int c0 = (idx & 15) * 4;
    float4 v = ((const float4*)H)[idx];
    float inv = 1.0f / (float)NN;
    float4 o;
    {
        float mu = stats[c0 + 0] * inv;
        float var = stats[64 + c0 + 0] * inv - mu * mu;
        float sc = gamma[c0 + 0] * rsqrtf(var + BN_EPS);
        float r = sc * (v.x - mu) + beta[c0 + 0];
        o.x = r > 0.f ? r : 0.f;
    }
    {
        float mu = stats[c0 + 1] * inv;
        float var = stats[64 + c0 + 1] * inv - mu * mu;
        float sc = gamma[c0 + 1] * rsqrtf(var + BN_EPS);
        float r = sc * (v.y - mu) + beta[c0 + 1];
        o.y = r > 0.f ? r : 0.f;
    }
    {
        float mu = stats[c0 + 2] * inv;
        float var = stats[64 + c0 + 2] * inv - mu * mu;
        float sc = gamma[c0 + 2] * rsqrtf(var + BN_EPS);
        float r = sc * (v.z - mu) + beta[c0 + 2];
        o.z = r > 0.f ? r : 0.f;
    }
    {
        float mu = stats[c0 + 3] * inv;
        float var = stats[64 + c0 + 3] * inv - mu * mu;
        float sc = gamma[c0 + 3] * rsqrtf(var + BN_EPS);
        float r = sc * (v.w - mu) + beta[c0 + 3];
        o.w = r > 0.f ? r : 0.f;
    }
    ((float4*)H)[idx] = o;
    ushort4 ob;
    ob.x = f32_to_bf16(o.x); ob.y = f32_to_bf16(o.y);
    ob.z = f32_to_bf16(o.z); ob.w = f32_to_bf16(o.w);
    ((ushort4*)Hb)[idx] = ob;
}

// ---------------- launch ----------------

static inline size_t alignup(size_t x) { return (x + 255) & ~(size_t)255; }

extern "C" void kernel_launch(void* const* d_in, const int* in_sizes, int n_in,
                              void* d_out, int out_size, void* d_ws, size_t ws_size,
                              hipStream_t stream) {
    const float* x      = (const float*)d_in[0];
    const int*   eidx   = (const int*)d_in[1];
    const int*   etype  = (const int*)d_in[2];
    const float* w1     = (const float*)d_in[3];
    const float* root1  = (const float*)d_in[4];
    const float* b1     = (const float*)d_in[5];
    const float* gamma1 = (const float*)d_in[6];
    const float* beta1  = (const float*)d_in[7];
    const float* w2     = (const float*)d_in[8];
    const float* root2  = (const float*)d_in[9];
    const float* b2     = (const float*)d_in[10];
    float* out = (float*)d_out;

    const int* src = eidx;
    const int* dst = eidx + EE;

    char* w = (char*)d_ws;
    int* rowptr = (int*)w;            w += alignup((size_t)(MM + 1) * 4);
    int* btot   = (int*)w;            w += alignup(512 * 4);
    int* bbase  = (int*)w;            w += alignup(512 * 4);
    int* gcur   = (int*)w;            w += alignup(512 * 4);
    int* rec    = (int*)w;            w += alignup((size_t)EE * 4);
    unsigned short* mean = (unsigned short*)w; w += alignup((size_t)NN * 512 * 2);
    float* h    = (float*)w;          w += alignup((size_t)NN * DD * 4);
    unsigned short* xhb = (unsigned short*)w; w += alignup((size_t)NN * DD * 2);
    unsigned short* wct1 = (unsigned short*)w; w += alignup((size_t)64 * KTOT * 2);
    unsigned short* wct2 = (unsigned short*)w; w += alignup((size_t)64 * KTOT * 2);
    float* stats = (float*)w;         w += alignup(128 * 4);
    unsigned int* ebuf = (unsigned int*)mean;   // alias: dead before k_agg writes mean

    hipMemsetAsync(btot, 0, 512 * 4, stream);
    hipMemsetAsync(stats, 0, 128 * 4, stream);

    // merged prep: wct1 | wct2 | tobf16 | bucket-count
    k_prep<<<dim3(2 * PREPW_BLKS + TOBF_BLKS + NBIN), dim3(256), 0, stream>>>(
        w1, root1, w2, root2, wct1, wct2, x, xhb, dst, btot);

    k_bscan<<<dim3(1), dim3(512), 0, stream>>>(btot, bbase, gcur, rowptr);
    k_bin<<<dim3(NBIN), dim3(256), 0, stream>>>(src, dst, etype, gcur, ebuf);
    k_bcsr<<<dim3(NB), dim3(256), 0, stream>>>(bbase, ebuf, rowptr, rec);

    // layer 1 (persistent-wave agg; gemm fuses BN column stats)
    k_agg<<<dim3(AGG_BLKS), dim3(256), 0, stream>>>(xhb, rowptr, rec, mean);
    k_gemm<<<dim3((NN + 127) / 128), dim3(256), 0, stream>>>(mean, xhb, wct1, b1, h, stats, 1);
    k_bnrelu<<<dim3(NN * DD / 4 / 256), dim3(256), 0, stream>>>(h, xhb, stats, gamma1, beta1);

    // layer 2 (xhb now holds bf16 of post-BN/ReLU h)
    k_agg<<<dim3(AGG_BLKS), dim3(256), 0, stream>>>(xhb, rowptr, rec, mean);
    k_gemm<<<dim3((NN + 127) / 128), dim3(256), 0, stream>>>(mean, xhb, wct2, b2, out, stats, 0);
}